// Round 2
// baseline (476.715 us; speedup 1.0000x reference)
//
#include <hip/hip_runtime.h>

#define KCODES 512
#define DDIM 64

// Pre-kernel: e_norm[k] = sum_d emb[k][d]^2  (512 floats into d_ws)
__global__ void vq_enorm_kernel(const float* __restrict__ emb, float* __restrict__ en) {
    int k = blockIdx.x * blockDim.x + threadIdx.x;
    if (k < KCODES) {
        float s = 0.f;
#pragma unroll
        for (int d = 0; d < DDIM; ++d) {
            float e = emb[k * DDIM + d];
            s = fmaf(e, e, s);
        }
        en[k] = s;
    }
}

// Block = 128 rows x 2 K-halves (256 threads). Thread (nl, ks) scans codes
// [ks*256, ks*256+256) for row base+nl; LDS pairwise argmin-reduce.
// z layout: [B, D, H, W] -> element (b, d, hw) at b*D*4096 + d*4096 + hw.
template <int KT>
__global__ __launch_bounds__(256, 4) void vq_argmin_kernel(
    const float* __restrict__ z, const float* __restrict__ emb,
    const float* __restrict__ en, int* __restrict__ out, int nrows) {
    const int tid = threadIdx.x;
    const int nl = tid & 127;          // row within block
    const int ks = tid >> 7;           // which K-half (0 or 1)
    const int n = blockIdx.x * 128 + nl;
    if (n >= nrows) return;
    const int b = n >> 12;             // H*W = 4096
    const int hw = n & 4095;
    const float* zp = z + (size_t)b * (DDIM * 4096) + hw;

    float zr[DDIM];
#pragma unroll
    for (int d = 0; d < DDIM; ++d) zr[d] = zp[(size_t)d * 4096];

    float zn = 0.f;
#pragma unroll
    for (int d = 0; d < DDIM; ++d) zn = fmaf(zr[d], zr[d], zn);

    float best = 3.4e38f;
    int bi = 0;
    const int kbeg = ks * (KCODES / 2);
    const int kend = kbeg + (KCODES / 2);
    for (int k0 = kbeg; k0 < kend; k0 += KT) {
        float acc[KT];
#pragma unroll
        for (int kk = 0; kk < KT; ++kk) acc[kk] = 0.f;
        const float* e0 = emb + k0 * DDIM;   // wave-uniform base -> s_load
#pragma unroll
        for (int d = 0; d < DDIM; ++d) {
            float zd = zr[d];
#pragma unroll
            for (int kk = 0; kk < KT; ++kk)
                acc[kk] = fmaf(e0[kk * DDIM + d], zd, acc[kk]);
        }
#pragma unroll
        for (int kk = 0; kk < KT; ++kk) {
            float dist = zn + en[k0 + kk] - 2.f * acc[kk];
            if (dist < best) { best = dist; bi = k0 + kk; }  // strict < = first-occurrence
        }
    }

    __shared__ float sb[2][128];
    __shared__ int   si[2][128];
    sb[ks][nl] = best;
    si[ks][nl] = bi;
    __syncthreads();
    if (ks == 0) {
        // lower-index half wins ties -> strict < when merging half 1
        if (sb[1][nl] < best) { best = sb[1][nl]; bi = si[1][nl]; }
        out[n] = bi;
    }
}

extern "C" void kernel_launch(void* const* d_in, const int* in_sizes, int n_in,
                              void* d_out, int out_size, void* d_ws, size_t ws_size,
                              hipStream_t stream) {
    const float* z   = (const float*)d_in[0];   // [32, 64, 64, 64] fp32
    const float* emb = (const float*)d_in[1];   // [512, 64] fp32
    int* out = (int*)d_out;                     // [32, 64, 64] int32
    float* en = (float*)d_ws;                   // 512 floats scratch

    vq_enorm_kernel<<<(KCODES + 255) / 256, 256, 0, stream>>>(emb, en);

    int nrows = out_size;                       // 131072
    int grid = (nrows + 127) / 128;             // 1024 blocks, 4096 waves
    vq_argmin_kernel<8><<<grid, 256, 0, stream>>>(z, emb, en, out, nrows);
}

// Round 3
// 152.063 us; speedup vs baseline: 3.1350x; 3.1350x over previous
//
#include <hip/hip_runtime.h>

#define KCODES 512
#define DDIM   64
#define HALF   256   // codes per K-half (one half per wave-pair)
#define TCODES 32    // codes per half per step
#define NSTEPS 8     // HALF / TCODES

typedef float float4v __attribute__((ext_vector_type(4)));

// Pre-kernel: e_norm[k] = sum_d emb[k][d]^2  (512 floats into d_ws)
__global__ void vq_enorm_kernel(const float* __restrict__ emb, float* __restrict__ en) {
    int k = blockIdx.x * blockDim.x + threadIdx.x;
    if (k < KCODES) {
        float s = 0.f;
#pragma unroll
        for (int d = 0; d < DDIM; ++d) { float e = emb[k * DDIM + d]; s = fmaf(e, e, s); }
        en[k] = s;
    }
}

// Block = 128 rows x 2 K-halves (256 thr). Codebook tiles staged in LDS
// (double-buffered, loads issued before compute), read back as broadcast
// ds_read_b128 -> inner loop is pure v_fmac v,v,v.
// z layout: [B, D, H, W] -> (b, d, hw) at b*D*4096 + d*4096 + hw.
__global__ __launch_bounds__(256, 4) void vq_argmin_kernel(
    const float* __restrict__ z, const float* __restrict__ emb,
    const float* __restrict__ en, int* __restrict__ out, int nrows) {

    __shared__ float4v et4[2][2][TCODES][DDIM / 4];  // [buf][half][code][d/4] = 32 KB
    __shared__ float   senorm[KCODES];               // 2 KB
    __shared__ float   sbest[2][128];
    __shared__ int     sbi[2][128];

    const int tid = threadIdx.x;
    const int nl  = tid & 127;      // row within block
    const int ks  = tid >> 7;       // K-half (uniform per wave: waves 0,1 -> 0; 2,3 -> 1)
    const int n   = blockIdx.x * 128 + nl;   // grid sized so n < nrows always (nrows % 128 == 0)
    const int b   = n >> 12;        // H*W = 4096
    const int hw  = n & 4095;
    const float* zp = z + (size_t)b * (DDIM * 4096) + hw;

    // e-norms -> LDS (once)
    senorm[tid]       = en[tid];
    senorm[tid + 256] = en[tid + 256];

    // z row -> registers (coalesced: lanes = consecutive hw)
    float zr[DDIM];
#pragma unroll
    for (int d = 0; d < DDIM; ++d) zr[d] = zp[(size_t)d * 4096];
    float zn = 0.f;
#pragma unroll
    for (int d = 0; d < DDIM; ++d) zn = fmaf(zr[d], zr[d], zn);

    // stage step 0: each thread copies 16 floats of its half's 32-code tile
    float4v stg0, stg1, stg2, stg3;
    {
        const float4v* s4 = (const float4v*)(emb + (ks * HALF) * DDIM) + nl * 4;
        stg0 = s4[0]; stg1 = s4[1]; stg2 = s4[2]; stg3 = s4[3];
        float4v* d4 = &et4[0][ks][0][0] + nl * 4;
        d4[0] = stg0; d4[1] = stg1; d4[2] = stg2; d4[3] = stg3;
    }
    __syncthreads();

    float best = 3.4e38f;
    int bi = 0;

    for (int t = 0; t < NSTEPS; ++t) {
        const int buf = t & 1;
        // issue next tile's global loads early; consumed after compute (latency hidden)
        if (t + 1 < NSTEPS) {
            const float4v* s4 =
                (const float4v*)(emb + (ks * HALF + (t + 1) * TCODES) * DDIM) + nl * 4;
            stg0 = s4[0]; stg1 = s4[1]; stg2 = s4[2]; stg3 = s4[3];
        }

        const float4v* eb = &et4[buf][ks][0][0];
        const int kbase = ks * HALF + t * TCODES;
        for (int kg = 0; kg < TCODES; kg += 4) {
            float acc0 = 0.f, acc1 = 0.f, acc2 = 0.f, acc3 = 0.f;
#pragma unroll
            for (int d = 0; d < DDIM; d += 4) {
                float4v e0 = eb[(kg + 0) * (DDIM / 4) + (d >> 2)];
                float4v e1 = eb[(kg + 1) * (DDIM / 4) + (d >> 2)];
                float4v e2 = eb[(kg + 2) * (DDIM / 4) + (d >> 2)];
                float4v e3 = eb[(kg + 3) * (DDIM / 4) + (d >> 2)];
#pragma unroll
                for (int i = 0; i < 4; ++i) {
                    acc0 = fmaf(e0[i], zr[d + i], acc0);
                    acc1 = fmaf(e1[i], zr[d + i], acc1);
                    acc2 = fmaf(e2[i], zr[d + i], acc2);
                    acc3 = fmaf(e3[i], zr[d + i], acc3);
                }
            }
            int k0 = kbase + kg;
            float dist0 = fmaf(-2.f, acc0, zn + senorm[k0 + 0]);
            float dist1 = fmaf(-2.f, acc1, zn + senorm[k0 + 1]);
            float dist2 = fmaf(-2.f, acc2, zn + senorm[k0 + 2]);
            float dist3 = fmaf(-2.f, acc3, zn + senorm[k0 + 3]);
            if (dist0 < best) { best = dist0; bi = k0 + 0; }  // strict < = first-occurrence
            if (dist1 < best) { best = dist1; bi = k0 + 1; }
            if (dist2 < best) { best = dist2; bi = k0 + 2; }
            if (dist3 < best) { best = dist3; bi = k0 + 3; }
        }

        // write next tile into the other buffer (other waves still read buf -> no overlap)
        if (t + 1 < NSTEPS) {
            float4v* d4 = &et4[buf ^ 1][ks][0][0] + nl * 4;
            d4[0] = stg0; d4[1] = stg1; d4[2] = stg2; d4[3] = stg3;
        }
        __syncthreads();
    }

    // merge the two K-halves (half 0 wins ties -> strict <)
    sbest[ks][nl] = best;
    sbi[ks][nl]   = bi;
    __syncthreads();
    if (ks == 0) {
        if (sbest[1][nl] < best) { best = sbest[1][nl]; bi = sbi[1][nl]; }
        if (n < nrows) out[n] = bi;
    }
}

extern "C" void kernel_launch(void* const* d_in, const int* in_sizes, int n_in,
                              void* d_out, int out_size, void* d_ws, size_t ws_size,
                              hipStream_t stream) {
    const float* z   = (const float*)d_in[0];   // [32, 64, 64, 64] fp32
    const float* emb = (const float*)d_in[1];   // [512, 64] fp32
    int* out = (int*)d_out;                     // [32, 64, 64] int32
    float* en = (float*)d_ws;                   // 512 floats scratch

    vq_enorm_kernel<<<(KCODES + 255) / 256, 256, 0, stream>>>(emb, en);

    int nrows = out_size;                       // 131072 (divisible by 128)
    int grid = nrows / 128;                     // 1024 blocks, 4096 waves
    vq_argmin_kernel<<<grid, 256, 0, stream>>>(z, emb, en, out, nrows);
}